// Round 1
// baseline (505.534 us; speedup 1.0000x reference)
//
#include <hip/hip_runtime.h>

// Problem constants (match reference)
#define BB 8
#define AA 120000
#define CC 80
#define MM 32

constexpr float ALPHA_ = 0.25f;
constexpr float POS_T_ = 0.5f;
constexpr float NEG_T_ = 0.4f;

// ws layout:
//   floats[0..7]   : c_sum per image
//   floats[8..15]  : r_sum per image
//   floats[16..23] : npos per image
//   byte offset 128: uint16 status[B*A]  (bit0-1: 0=neg,1=ignore,2=pos; bits 2+: assigned class)

__global__ void init_acc_kernel(float* __restrict__ acc) {
    int t = threadIdx.x;
    if (t < 24) acc[t] = 0.0f;
}

__global__ void assign_kernel(const float* __restrict__ anchors,
                              const float* __restrict__ regressions,
                              const float* __restrict__ labels,
                              float* __restrict__ acc,
                              unsigned short* __restrict__ status) {
    const int b = blockIdx.y;
    const int a = blockIdx.x * blockDim.x + threadIdx.x;

    __shared__ float lb[MM * 5];
    __shared__ float blk_r, blk_n;
    if (threadIdx.x < MM * 5) lb[threadIdx.x] = labels[b * MM * 5 + threadIdx.x];
    if (threadIdx.x == 0) { blk_r = 0.0f; blk_n = 0.0f; }
    __syncthreads();

    float r_contrib = 0.0f, n_contrib = 0.0f;

    if (a < AA) {
        const float4 an = ((const float4*)anchors)[a];
        const float aw = an.z - an.x;
        const float ah = an.w - an.y;
        const float area_a = aw * ah;

        float best = -1e30f;
        int arg = 0;
        #pragma unroll 8
        for (int m = 0; m < MM; ++m) {
            const float bx1 = lb[m * 5 + 0], by1 = lb[m * 5 + 1];
            const float bx2 = lb[m * 5 + 2], by2 = lb[m * 5 + 3];
            float v;
            if (lb[m * 5 + 4] == -1.0f) {
                v = -1.0f;
            } else {
                float iw = fminf(an.z, bx2) - fmaxf(an.x, bx1);
                iw = fmaxf(iw, 0.0f);
                float ih = fminf(an.w, by2) - fmaxf(an.y, by1);
                ih = fmaxf(ih, 0.0f);
                const float inter = iw * ih;
                const float ua = fmaxf(area_a + (bx2 - bx1) * (by2 - by1) - inter, 1e-8f);
                v = inter / ua;
            }
            if (v > best) { best = v; arg = m; }  // strict > == first-occurrence argmax
        }

        const bool pos = best >= POS_T_;
        const bool neg = best < NEG_T_;
        const int acls = (int)lb[arg * 5 + 4];
        unsigned short st = pos ? (unsigned short)(2 | (acls << 2)) : (neg ? 0 : 1);
        status[(size_t)b * AA + a] = st;

        if (pos) {
            n_contrib = 1.0f;
            const float gx1 = lb[arg * 5 + 0], gy1 = lb[arg * 5 + 1];
            const float gx2 = lb[arg * 5 + 2], gy2 = lb[arg * 5 + 3];
            const float gwr = gx2 - gx1, ghr = gy2 - gy1;
            const float gcx = gx1 + 0.5f * gwr, gcy = gy1 + 0.5f * ghr;
            const float gw = fmaxf(gwr, 1.0f), gh = fmaxf(ghr, 1.0f);
            const float acx = an.x + 0.5f * aw, acy = an.y + 0.5f * ah;

            const float t0 = ((gcx - acx) / aw) / 0.1f;
            const float t1 = ((gcy - acy) / ah) / 0.1f;
            const float t2 = logf(gw / aw) / 0.2f;
            const float t3 = logf(gh / ah) / 0.2f;

            const float4 rg = ((const float4*)regressions)[(size_t)b * AA + a];
            const float d0 = fabsf(t0 - rg.x);
            const float d1 = fabsf(t1 - rg.y);
            const float d2 = fabsf(t2 - rg.z);
            const float d3 = fabsf(t3 - rg.w);
            const float bnd = 1.0f / 9.0f;
            const float hb  = 0.5f / 9.0f;
            r_contrib  = (d0 <= bnd) ? 4.5f * d0 * d0 : d0 - hb;
            r_contrib += (d1 <= bnd) ? 4.5f * d1 * d1 : d1 - hb;
            r_contrib += (d2 <= bnd) ? 4.5f * d2 * d2 : d2 - hb;
            r_contrib += (d3 <= bnd) ? 4.5f * d3 * d3 : d3 - hb;
        }
    }

    // wave(64) reduce, then LDS, then one global atomic per block
    #pragma unroll
    for (int off = 32; off > 0; off >>= 1) {
        r_contrib += __shfl_down(r_contrib, off);
        n_contrib += __shfl_down(n_contrib, off);
    }
    if ((threadIdx.x & 63) == 0) {
        atomicAdd(&blk_r, r_contrib);
        atomicAdd(&blk_n, n_contrib);
    }
    __syncthreads();
    if (threadIdx.x == 0) {
        if (blk_r != 0.0f) atomicAdd(&acc[8 + b], blk_r);
        if (blk_n != 0.0f) atomicAdd(&acc[16 + b], blk_n);
    }
}

#define IPT 8
#define F4_PER_IMG (AA * CC / 4)  // 2,400,000 float4 per image

__global__ __launch_bounds__(256) void cls_loss_kernel(
        const float* __restrict__ cls,
        const unsigned short* __restrict__ status,
        float* __restrict__ acc) {
    const int b = blockIdx.y;
    const float4* __restrict__ cp = (const float4*)(cls + (size_t)b * AA * CC);
    const unsigned short* __restrict__ stp = status + (size_t)b * AA;

    float sum = 0.0f;
    const int base = blockIdx.x * (256 * IPT) + threadIdx.x;

    #pragma unroll
    for (int i = 0; i < IPT; ++i) {
        const int j = base + i * 256;
        if (j < F4_PER_IMG) {
            const int a = j / 20;           // 20 float4 per anchor row (C=80)
            const unsigned short st = stp[a];
            const int s = st & 3;
            if (s != 1) {                    // skip ignore anchors entirely
                const float4 p4 = cp[j];
                const int cbase = (j % 20) * 4;
                const int acls = (s == 2) ? (int)(st >> 2) : -1;
                const float pv[4] = {p4.x, p4.y, p4.z, p4.w};
                #pragma unroll
                for (int k = 0; k < 4; ++k) {
                    const float p = fminf(fmaxf(pv[k], 1e-4f), 1.0f - 1e-4f);
                    if (cbase + k == acls) {
                        const float q = 1.0f - p;
                        sum += ALPHA_ * q * q * (-__logf(p));
                    } else {
                        sum += (1.0f - ALPHA_) * p * p * (-__logf(1.0f - p));
                    }
                }
            }
        }
    }

    // block reduce: wave shuffle then LDS
    #pragma unroll
    for (int off = 32; off > 0; off >>= 1) sum += __shfl_down(sum, off);
    __shared__ float wsum[4];
    const int wid = threadIdx.x >> 6;
    if ((threadIdx.x & 63) == 0) wsum[wid] = sum;
    __syncthreads();
    if (threadIdx.x == 0) {
        atomicAdd(&acc[b], wsum[0] + wsum[1] + wsum[2] + wsum[3]);
    }
}

__global__ void finalize_kernel(const float* __restrict__ acc, float* __restrict__ out) {
    if (threadIdx.x == 0 && blockIdx.x == 0) {
        float cm = 0.0f, rm = 0.0f;
        #pragma unroll
        for (int b = 0; b < BB; ++b) {
            const float np_ = acc[16 + b];
            cm += acc[b] / fmaxf(np_, 1.0f);
            rm += (np_ > 0.0f) ? acc[8 + b] / (np_ * 4.0f) : 0.0f;
        }
        out[0] = cm / (float)BB;
        out[1] = rm / (float)BB;
    }
}

extern "C" void kernel_launch(void* const* d_in, const int* in_sizes, int n_in,
                              void* d_out, int out_size, void* d_ws, size_t ws_size,
                              hipStream_t stream) {
    const float* classifications = (const float*)d_in[0];  // [B,A,C]
    const float* regressions     = (const float*)d_in[1];  // [B,A,4]
    const float* anchors         = (const float*)d_in[2];  // [1,A,4]
    const float* labels          = (const float*)d_in[3];  // [B,M,5]
    float* out = (float*)d_out;

    float* acc = (float*)d_ws;
    unsigned short* status = (unsigned short*)((char*)d_ws + 128);

    init_acc_kernel<<<1, 32, 0, stream>>>(acc);

    dim3 g1((AA + 255) / 256, BB);
    assign_kernel<<<g1, 256, 0, stream>>>(anchors, regressions, labels, acc, status);

    dim3 g2((F4_PER_IMG + 256 * IPT - 1) / (256 * IPT), BB);
    cls_loss_kernel<<<g2, 256, 0, stream>>>(classifications, status, acc);

    finalize_kernel<<<1, 64, 0, stream>>>(acc, out);
}

// Round 4
// 465.770 us; speedup vs baseline: 1.0854x; 1.0854x over previous
//
#include <hip/hip_runtime.h>

// Problem constants (match reference)
#define BB 8
#define AA 120000
#define CC 80
#define MM 32

// Fused tiling: 192 anchors per block (625 * 192 = 120000 exactly),
// 256 threads, phase2 sweeps 192*20 = 3840 float4 in 15 exact iters.
#define APB 192
#define F4B (APB * 20)
#define NBLK (AA / APB)

constexpr float ALPHA_ = 0.25f;
constexpr float POS_T_ = 0.5f;
constexpr float NEG_T_ = 0.4f;

// ws layout (floats): [0..7] c_sum, [8..15] r_sum, [16..23] npos per image

__global__ void init_acc_kernel(float* __restrict__ acc) {
    int t = threadIdx.x;
    if (t < 24) acc[t] = 0.0f;
}

__global__ __launch_bounds__(256) void fused_kernel(
        const float* __restrict__ anchors,
        const float* __restrict__ cls,
        const float* __restrict__ regressions,
        const float* __restrict__ labels,
        float* __restrict__ acc) {
    const int b  = blockIdx.y;
    const int a0 = blockIdx.x * APB;
    const int t  = threadIdx.x;

    __shared__ float lb[MM * 5];
    __shared__ unsigned short sst[APB];   // status: bits0-1 (0=neg,1=ign,2=pos), bits2+ class
    __shared__ float wred[2][4];

    if (t < MM * 5) lb[t] = labels[b * MM * 5 + t];
    __syncthreads();

    // ---------------- phase 1: assignment + regression loss (192 threads) ---
    float r_c = 0.0f, n_c = 0.0f;
    if (t < APB) {
        const int a = a0 + t;
        const float4 an = ((const float4*)anchors)[a];
        const float aw = an.z - an.x;
        const float ah = an.w - an.y;
        const float area_a = aw * ah;

        float best = -1e30f;
        int arg = 0;
        #pragma unroll 8
        for (int m = 0; m < MM; ++m) {
            const float bx1 = lb[m * 5 + 0], by1 = lb[m * 5 + 1];
            const float bx2 = lb[m * 5 + 2], by2 = lb[m * 5 + 3];
            float v;
            if (lb[m * 5 + 4] == -1.0f) {
                v = -1.0f;
            } else {
                float iw = fmaxf(fminf(an.z, bx2) - fmaxf(an.x, bx1), 0.0f);
                float ih = fmaxf(fminf(an.w, by2) - fmaxf(an.y, by1), 0.0f);
                const float inter = iw * ih;
                const float ua = fmaxf(area_a + (bx2 - bx1) * (by2 - by1) - inter, 1e-8f);
                v = inter / ua;
            }
            if (v > best) { best = v; arg = m; }   // strict > == first-occurrence argmax
        }

        const bool pos = best >= POS_T_;
        const bool neg = best < NEG_T_;
        const int acls = (int)lb[arg * 5 + 4];
        sst[t] = pos ? (unsigned short)(2 | (acls << 2)) : (neg ? (unsigned short)0 : (unsigned short)1);

        if (pos) {
            n_c = 1.0f;
            const float gx1 = lb[arg * 5 + 0], gy1 = lb[arg * 5 + 1];
            const float gx2 = lb[arg * 5 + 2], gy2 = lb[arg * 5 + 3];
            const float gwr = gx2 - gx1, ghr = gy2 - gy1;
            const float gcx = gx1 + 0.5f * gwr, gcy = gy1 + 0.5f * ghr;
            const float gw = fmaxf(gwr, 1.0f), gh = fmaxf(ghr, 1.0f);
            const float acx = an.x + 0.5f * aw, acy = an.y + 0.5f * ah;

            const float t0 = ((gcx - acx) / aw) * 10.0f;
            const float t1 = ((gcy - acy) / ah) * 10.0f;
            const float t2 = logf(gw / aw) * 5.0f;
            const float t3 = logf(gh / ah) * 5.0f;

            const float4 rg = ((const float4*)regressions)[(size_t)b * AA + a];
            const float d0 = fabsf(t0 - rg.x);
            const float d1 = fabsf(t1 - rg.y);
            const float d2 = fabsf(t2 - rg.z);
            const float d3 = fabsf(t3 - rg.w);
            const float bnd = 1.0f / 9.0f;
            const float hb  = 0.5f / 9.0f;
            r_c  = (d0 <= bnd) ? 4.5f * d0 * d0 : d0 - hb;
            r_c += (d1 <= bnd) ? 4.5f * d1 * d1 : d1 - hb;
            r_c += (d2 <= bnd) ? 4.5f * d2 * d2 : d2 - hb;
            r_c += (d3 <= bnd) ? 4.5f * d3 * d3 : d3 - hb;
        }
    }

    // block reduce r_c, n_c (also publishes sst via the barrier)
    #pragma unroll
    for (int off = 32; off > 0; off >>= 1) {
        r_c += __shfl_down(r_c, off);
        n_c += __shfl_down(n_c, off);
    }
    const int wid = t >> 6;
    if ((t & 63) == 0) { wred[0][wid] = r_c; wred[1][wid] = n_c; }
    __syncthreads();
    if (t == 0) {
        const float rs = wred[0][0] + wred[0][1] + wred[0][2] + wred[0][3];
        const float ns = wred[1][0] + wred[1][1] + wred[1][2] + wred[1][3];
        if (rs != 0.0f) atomicAdd(&acc[8 + b], rs);
        if (ns != 0.0f) atomicAdd(&acc[16 + b], ns);
    }

    // ---------------- phase 2: classification focal loss over 192x80 --------
    const float4* __restrict__ cp =
        (const float4*)(cls + (size_t)b * AA * CC) + (size_t)a0 * 20;

    float sum = 0.0f;
    #pragma unroll
    for (int i = 0; i < F4B / 256; ++i) {           // 15 exact iterations
        const int j = i * 256 + t;                  // < 3840
        const int a = j / 20;                       // local anchor
        const unsigned short st = sst[a];
        const int s = st & 3;
        if (s != 1) {                               // skip ignore anchors
            const float4 p4 = cp[j];
            const int cbase = (j - a * 20) * 4;
            const int acls = (s == 2) ? (int)(st >> 2) : -1;
            const float pv[4] = {p4.x, p4.y, p4.z, p4.w};
            #pragma unroll
            for (int k = 0; k < 4; ++k) {
                const float p = fminf(fmaxf(pv[k], 1e-4f), 1.0f - 1e-4f);
                if (cbase + k == acls) {
                    const float q = 1.0f - p;
                    sum += ALPHA_ * q * q * (-__logf(p));
                } else {
                    sum += (1.0f - ALPHA_) * p * p * (-__logf(1.0f - p));
                }
            }
        }
    }

    #pragma unroll
    for (int off = 32; off > 0; off >>= 1) sum += __shfl_down(sum, off);
    __syncthreads();                                // reuse wred
    if ((t & 63) == 0) wred[0][wid] = sum;
    __syncthreads();
    if (t == 0) {
        atomicAdd(&acc[b], wred[0][0] + wred[0][1] + wred[0][2] + wred[0][3]);
    }
}

__global__ void finalize_kernel(const float* __restrict__ acc, float* __restrict__ out) {
    if (threadIdx.x == 0 && blockIdx.x == 0) {
        float cm = 0.0f, rm = 0.0f;
        #pragma unroll
        for (int b = 0; b < BB; ++b) {
            const float np_ = acc[16 + b];
            cm += acc[b] / fmaxf(np_, 1.0f);
            rm += (np_ > 0.0f) ? acc[8 + b] / (np_ * 4.0f) : 0.0f;
        }
        out[0] = cm / (float)BB;
        out[1] = rm / (float)BB;
    }
}

extern "C" void kernel_launch(void* const* d_in, const int* in_sizes, int n_in,
                              void* d_out, int out_size, void* d_ws, size_t ws_size,
                              hipStream_t stream) {
    const float* classifications = (const float*)d_in[0];  // [B,A,C]
    const float* regressions     = (const float*)d_in[1];  // [B,A,4]
    const float* anchors         = (const float*)d_in[2];  // [1,A,4]
    const float* labels          = (const float*)d_in[3];  // [B,M,5]
    float* out = (float*)d_out;
    float* acc = (float*)d_ws;

    init_acc_kernel<<<1, 32, 0, stream>>>(acc);

    dim3 g(NBLK, BB);
    fused_kernel<<<g, 256, 0, stream>>>(anchors, classifications, regressions, labels, acc);

    finalize_kernel<<<1, 64, 0, stream>>>(acc, out);
}

// Round 6
// 436.184 us; speedup vs baseline: 1.1590x; 1.0678x over previous
//
#include <hip/hip_runtime.h>

// Problem constants (match reference)
#define BB 8
#define AA 120000
#define CC 80
#define MM 32

// Fused tiling: 192 anchors per block (625 * 192 = 120000 exactly),
// 256 threads, phase2 sweeps 192*20 = 3840 float4 in 15 exact iters.
#define APB 192
#define F4B (APB * 20)
#define NBLK (AA / APB)   // 625

constexpr float ALPHA_ = 0.25f;
constexpr float POS_T_ = 0.5f;
constexpr float NEG_T_ = 0.4f;

// ws layout (floats): cpart[BB*NBLK], rpart[BB*NBLK], npart[BB*NBLK]
// Every block writes its own slot -> no zero-init kernel needed (0xAA poison
// is overwritten before finalize reads it).

__global__ __launch_bounds__(256) void fused_kernel(
        const float* __restrict__ anchors,
        const float* __restrict__ cls,
        const float* __restrict__ regressions,
        const float* __restrict__ labels,
        float* __restrict__ cpart,
        float* __restrict__ rpart,
        float* __restrict__ npart) {
    const int b  = blockIdx.y;
    const int a0 = blockIdx.x * APB;
    const int t  = threadIdx.x;
    const int slot = b * NBLK + blockIdx.x;

    __shared__ float lb[MM * 5];
    __shared__ unsigned short sst[APB];   // status: bits0-1 (0=neg,1=ign,2=pos), bits2+ class
    __shared__ float wred[2][4];

    if (t < MM * 5) lb[t] = labels[b * MM * 5 + t];
    __syncthreads();

    // ---------------- phase 1: assignment + regression loss (192 threads) ---
    float r_c = 0.0f, n_c = 0.0f;
    if (t < APB) {
        const int a = a0 + t;
        const float4 an = ((const float4*)anchors)[a];
        const float aw = an.z - an.x;
        const float ah = an.w - an.y;
        const float area_a = aw * ah;

        float best = -1e30f;
        int arg = 0;
        #pragma unroll 8
        for (int m = 0; m < MM; ++m) {
            const float bx1 = lb[m * 5 + 0], by1 = lb[m * 5 + 1];
            const float bx2 = lb[m * 5 + 2], by2 = lb[m * 5 + 3];
            float v;
            if (lb[m * 5 + 4] == -1.0f) {
                v = -1.0f;
            } else {
                float iw = fmaxf(fminf(an.z, bx2) - fmaxf(an.x, bx1), 0.0f);
                float ih = fmaxf(fminf(an.w, by2) - fmaxf(an.y, by1), 0.0f);
                const float inter = iw * ih;
                const float ua = fmaxf(area_a + (bx2 - bx1) * (by2 - by1) - inter, 1e-8f);
                v = inter / ua;
            }
            if (v > best) { best = v; arg = m; }   // strict > == first-occurrence argmax
        }

        const bool pos = best >= POS_T_;
        const bool neg = best < NEG_T_;
        const int acls = (int)lb[arg * 5 + 4];
        sst[t] = pos ? (unsigned short)(2 | (acls << 2)) : (neg ? (unsigned short)0 : (unsigned short)1);

        if (pos) {
            n_c = 1.0f;
            const float gx1 = lb[arg * 5 + 0], gy1 = lb[arg * 5 + 1];
            const float gx2 = lb[arg * 5 + 2], gy2 = lb[arg * 5 + 3];
            const float gwr = gx2 - gx1, ghr = gy2 - gy1;
            const float gcx = gx1 + 0.5f * gwr, gcy = gy1 + 0.5f * ghr;
            const float gw = fmaxf(gwr, 1.0f), gh = fmaxf(ghr, 1.0f);
            const float acx = an.x + 0.5f * aw, acy = an.y + 0.5f * ah;

            const float t0 = ((gcx - acx) / aw) * 10.0f;
            const float t1 = ((gcy - acy) / ah) * 10.0f;
            const float t2 = logf(gw / aw) * 5.0f;
            const float t3 = logf(gh / ah) * 5.0f;

            const float4 rg = ((const float4*)regressions)[(size_t)b * AA + a];
            const float d0 = fabsf(t0 - rg.x);
            const float d1 = fabsf(t1 - rg.y);
            const float d2 = fabsf(t2 - rg.z);
            const float d3 = fabsf(t3 - rg.w);
            const float bnd = 1.0f / 9.0f;
            const float hb  = 0.5f / 9.0f;
            r_c  = (d0 <= bnd) ? 4.5f * d0 * d0 : d0 - hb;
            r_c += (d1 <= bnd) ? 4.5f * d1 * d1 : d1 - hb;
            r_c += (d2 <= bnd) ? 4.5f * d2 * d2 : d2 - hb;
            r_c += (d3 <= bnd) ? 4.5f * d3 * d3 : d3 - hb;
        }
    }

    // block reduce r_c, n_c (barrier also publishes sst for phase 2)
    #pragma unroll
    for (int off = 32; off > 0; off >>= 1) {
        r_c += __shfl_down(r_c, off);
        n_c += __shfl_down(n_c, off);
    }
    const int wid = t >> 6;
    if ((t & 63) == 0) { wred[0][wid] = r_c; wred[1][wid] = n_c; }
    __syncthreads();
    float rs_ = 0.0f, ns_ = 0.0f;
    if (t == 0) {
        rs_ = wred[0][0] + wred[0][1] + wred[0][2] + wred[0][3];
        ns_ = wred[1][0] + wred[1][1] + wred[1][2] + wred[1][3];
    }

    // ---------------- phase 2: classification focal loss over 192x80 --------
    const float4* __restrict__ cp =
        (const float4*)(cls + (size_t)b * AA * CC) + (size_t)a0 * 20;

    float sum = 0.0f;
    #pragma unroll
    for (int i = 0; i < F4B / 256; ++i) {           // 15 exact iterations
        const int j = i * 256 + t;                  // < 3840
        const int a = j / 20;                       // local anchor
        const unsigned short st = sst[a];
        const int s = st & 3;
        if (s != 1) {                               // skip ignore anchors
            const float4 p4 = cp[j];
            const int cbase = (j - a * 20) * 4;
            const int acls = (s == 2) ? (int)(st >> 2) : -1;
            const float pv[4] = {p4.x, p4.y, p4.z, p4.w};
            #pragma unroll
            for (int k = 0; k < 4; ++k) {
                const float p = fminf(fmaxf(pv[k], 1e-4f), 1.0f - 1e-4f);
                if (cbase + k == acls) {
                    const float q = 1.0f - p;
                    sum += ALPHA_ * q * q * (-__logf(p));
                } else {
                    sum += (1.0f - ALPHA_) * p * p * (-__logf(1.0f - p));
                }
            }
        }
    }

    #pragma unroll
    for (int off = 32; off > 0; off >>= 1) sum += __shfl_down(sum, off);
    __syncthreads();                                // reuse wred
    if ((t & 63) == 0) wred[0][wid] = sum;
    __syncthreads();
    if (t == 0) {
        cpart[slot] = wred[0][0] + wred[0][1] + wred[0][2] + wred[0][3];
        rpart[slot] = rs_;
        npart[slot] = ns_;
    }
}

// 512 threads = 8 waves; wave w reduces image w's 625 partials.
__global__ __launch_bounds__(512) void finalize_kernel(
        const float* __restrict__ cpart,
        const float* __restrict__ rpart,
        const float* __restrict__ npart,
        float* __restrict__ out) {
    const int w = threadIdx.x >> 6;   // image index
    const int l = threadIdx.x & 63;

    float cs = 0.0f, rs = 0.0f, ns = 0.0f;
    for (int i = l; i < NBLK; i += 64) {
        const int s = w * NBLK + i;
        cs += cpart[s];
        rs += rpart[s];
        ns += npart[s];
    }
    #pragma unroll
    for (int off = 32; off > 0; off >>= 1) {
        cs += __shfl_down(cs, off);
        rs += __shfl_down(rs, off);
        ns += __shfl_down(ns, off);
    }

    __shared__ float sc[8], sr[8];
    if (l == 0) {
        sc[w] = cs / fmaxf(ns, 1.0f);
        sr[w] = (ns > 0.0f) ? rs / (ns * 4.0f) : 0.0f;
    }
    __syncthreads();
    if (threadIdx.x == 0) {
        float cm = 0.0f, rm = 0.0f;
        #pragma unroll
        for (int b = 0; b < BB; ++b) { cm += sc[b]; rm += sr[b]; }
        out[0] = cm / (float)BB;
        out[1] = rm / (float)BB;
    }
}

extern "C" void kernel_launch(void* const* d_in, const int* in_sizes, int n_in,
                              void* d_out, int out_size, void* d_ws, size_t ws_size,
                              hipStream_t stream) {
    const float* classifications = (const float*)d_in[0];  // [B,A,C]
    const float* regressions     = (const float*)d_in[1];  // [B,A,4]
    const float* anchors         = (const float*)d_in[2];  // [1,A,4]
    const float* labels          = (const float*)d_in[3];  // [B,M,5]
    float* out = (float*)d_out;

    float* ws    = (float*)d_ws;
    float* cpart = ws;
    float* rpart = ws + BB * NBLK;
    float* npart = ws + 2 * BB * NBLK;

    dim3 g(NBLK, BB);
    fused_kernel<<<g, 256, 0, stream>>>(anchors, classifications, regressions, labels,
                                        cpart, rpart, npart);
    finalize_kernel<<<1, 512, 0, stream>>>(cpart, rpart, npart, out);
}